// Round 4
// baseline (234.237 us; speedup 1.0000x reference)
//
#include <hip/hip_runtime.h>
#include <hip/hip_bf16.h>

// Linear1d: out[B,256] = (x[B,512] @ W[256,512]^T) / 8 + 0.1*bias
// R8: break the barrier drain. R5->R7 all pin at ~80us because __syncthreads
// emits s_waitcnt vmcnt(0) -- the x prefetch never outlives a chunk, so
// in-flight bytes duty-cycle to ~20KB/CU -> 2.5 TB/s. Replace with
// {s_waitcnt lgkmcnt(0); s_barrier; sched_barrier(0)} (m201/T3+T4 pattern:
// LDS visibility kept, vmcnt NEVER drained in-loop) and deepen prefetch to
// 2 chunks via two named reg sets rA/rB (static indexing, rule #20).
// Also: pair the two N-half blocks as {g, g+8} so they land on the SAME XCD
// (mod-8 round-robin) and the second half's x reads are L2 hits
// (R7's consecutive pairing doubled FETCH to 132MB).

typedef __bf16 bf16;
typedef __attribute__((ext_vector_type(8))) __bf16 bf16x8;
typedef __attribute__((ext_vector_type(4))) __bf16 bf16x4;
typedef __attribute__((ext_vector_type(4))) float f32x4;

#define BATCH_ 65536
#define KDIM   512
#define NDIM   256
#define NHALF  128                 // N-cols per block
#define CHUNK_ROWS 16
#define CHUNKS 8                   // per block
#define ROWS_PER_BLOCK (CHUNK_ROWS * CHUNKS)   // 128

__global__ __launch_bounds__(256) void wcvt_kernel(const float* __restrict__ w,
                                                   bf16* __restrict__ wb) {
    int i = (blockIdx.x * 256 + threadIdx.x) * 4;
    f32x4 v = *(const f32x4*)(w + i);
    bf16x4 o;
    o[0] = (bf16)(v.x * 0.125f);
    o[1] = (bf16)(v.y * 0.125f);
    o[2] = (bf16)(v.z * 0.125f);
    o[3] = (bf16)(v.w * 0.125f);
    *(bf16x4*)(wb + i) = o;
}

// Issue 4 perfectly-linear global loads (64 B/thread, block covers 32 KB f32).
__device__ __forceinline__ void stage_issue(const float* xc, int tid, f32x4 (&r)[4]) {
#pragma unroll
    for (int i = 0; i < 4; ++i)
        r[i] = *(const f32x4*)((const char*)xc + i * 8192 + tid * 16);
}

// Convert to bf16, deposit into LDS with the bank swizzle.
// Thread t, pass i holds f32 elems [i*2048 + t*4 .. +4) -> logical bf16 byte
// L = i*4096 + t*8; row = i*4 + (t>>7); off = (t&127)*8;
// phys = row*1024 + (off ^ ((row&7)<<4)).  (row wave-uniform per pass.)
__device__ __forceinline__ void stage_write(bf16* buf, int tid, const f32x4 (&r)[4]) {
#pragma unroll
    for (int i = 0; i < 4; ++i) {
        const int row = i * 4 + (tid >> 7);
        const int off = (tid & 127) * 8;
        const int phys = row * 1024 + (off ^ ((row & 7) << 4));
        bf16x4 o;
        o[0] = (bf16)r[i].x;
        o[1] = (bf16)r[i].y;
        o[2] = (bf16)r[i].z;
        o[3] = (bf16)r[i].w;
        *(bf16x4*)((char*)buf + phys) = o;
    }
}

// Pure ds_read_b128 + MFMA, swizzled to spread l16 lanes across bank quads.
__device__ __forceinline__ void compute_chunk(const bf16* buf, const bf16x8 (&wf)[16],
                                              int l16, int q, f32x4& acc) {
    acc = (f32x4)0.0f;
    const char* base = (const char*)buf + l16 * 1024;
    const int xo = (l16 & 7) << 4;
#pragma unroll
    for (int kc = 0; kc < 16; ++kc) {
        bf16x8 a = *(const bf16x8*)(base + ((kc * 64 + q * 16) ^ xo));
        acc = __builtin_amdgcn_mfma_f32_16x16x32_bf16(a, wf[kc], acc, 0, 0, 0);
    }
}

// LDS-visibility barrier WITHOUT the vmcnt(0) drain __syncthreads would emit.
__device__ __forceinline__ void lds_barrier() {
    asm volatile("s_waitcnt lgkmcnt(0)" ::: "memory");
    __builtin_amdgcn_s_barrier();
    __builtin_amdgcn_sched_barrier(0);   // no ds_read hoisted above the barrier
}

__global__ __launch_bounds__(512, 4) void gemm_kernel(const float* __restrict__ x,
                                                      const bf16* __restrict__ wb,
                                                      const float* __restrict__ bias,
                                                      float* __restrict__ out) {
    __shared__ __align__(16) bf16 bufA[CHUNK_ROWS * KDIM];  // 16 KB
    __shared__ __align__(16) bf16 bufB[CHUNK_ROWS * KDIM];  // 16 KB

    const int tid  = threadIdx.x;
    const int lane = tid & 63;
    const int w    = tid >> 6;     // wave 0..7 -> 16 N-columns each
    const int q    = lane >> 4;
    const int l16  = lane & 15;

    // Pair N-halves on the SAME XCD: g and g^8 share rb, differ in half.
    const int g    = blockIdx.x;
    const int half = (g >> 3) & 1;
    const long rb  = (long)((g & 7) | ((g >> 4) << 3));
    const int n0   = half * NHALF + w * 16;
    const long row_base = rb * ROWS_PER_BLOCK;

    // Stationary W: wf[kc] = W[n0+l16][kc*32+q*8 .. +7]  (64 regs/wave)
    bf16x8 wf[16];
#pragma unroll
    for (int kc = 0; kc < 16; ++kc)
        wf[kc] = *(const bf16x8*)(wb + (long)(n0 + l16) * KDIM + kc * 32 + q * 8);
    const float bv = 0.1f * bias[n0 + l16];

    const float* xblk = x + row_base * KDIM;

    // Prologue: c0 -> rA -> bufA; c1 -> rB (stays in flight across barrier).
    f32x4 rA[4], rB[4];
    stage_issue(xblk, tid, rA);
    stage_issue(xblk + 1 * CHUNK_ROWS * KDIM, tid, rB);
    stage_write(bufA, tid, rA);        // counted vmcnt: waits rA only
    lds_barrier();

    f32x4 acc;
#pragma unroll 1
    for (int t = 0; t < CHUNKS; t += 2) {
        // ---- even: compute c(t)=bufA; write c(t+1)=rB->bufB; issue c(t+2)->rA
        if (t + 2 < CHUNKS)
            stage_issue(xblk + (long)(t + 2) * CHUNK_ROWS * KDIM, tid, rA);
        compute_chunk(bufA, wf, l16, q, acc);
        stage_write(bufB, tid, rB);    // counted vmcnt: rA (and stores) stay in flight
        lds_barrier();
        {
            const long row0 = row_base + (long)t * CHUNK_ROWS;
#pragma unroll
            for (int rr = 0; rr < 4; ++rr)
                out[(row0 + q * 4 + rr) * NDIM + n0 + l16] = acc[rr] + bv;
        }

        // ---- odd: compute c(t+1)=bufB; write c(t+2)=rA->bufA; issue c(t+3)->rB
        if (t + 3 < CHUNKS)
            stage_issue(xblk + (long)(t + 3) * CHUNK_ROWS * KDIM, tid, rB);
        compute_chunk(bufB, wf, l16, q, acc);
        if (t + 2 < CHUNKS)
            stage_write(bufA, tid, rA);
        lds_barrier();
        {
            const long row0 = row_base + (long)(t + 1) * CHUNK_ROWS;
#pragma unroll
            for (int rr = 0; rr < 4; ++rr)
                out[(row0 + q * 4 + rr) * NDIM + n0 + l16] = acc[rr] + bv;
        }
    }
}

extern "C" void kernel_launch(void* const* d_in, const int* in_sizes, int n_in,
                              void* d_out, int out_size, void* d_ws, size_t ws_size,
                              hipStream_t stream) {
    const float* x    = (const float*)d_in[0];
    const float* w    = (const float*)d_in[1];
    const float* bias = (const float*)d_in[2];
    float* out = (float*)d_out;
    bf16* wb   = (bf16*)d_ws;   // 256*512*2 = 256 KB scratch

    wcvt_kernel<<<(NDIM * KDIM) / (256 * 4), 256, 0, stream>>>(w, wb);
    gemm_kernel<<<(BATCH_ / ROWS_PER_BLOCK) * 2, 512, 0, stream>>>(x, wb, bias, out);
}

// Round 5
// 223.434 us; speedup vs baseline: 1.0484x; 1.0484x over previous
//
#include <hip/hip_runtime.h>
#include <hip/hip_bf16.h>

// Linear1d: out[B,256] = (x[B,512] @ W[256,512]^T) / 8 + 0.1*bias
// R9: coalesced-store epilogue. R4-R8 all pin at 80-86us across radically
// different load/pipeline structures; the shared invariant is the store
// pattern (each global_store_dword = 4 scattered 64B half-line segments,
// ~256K granule-cycles/CU ~= the observed floor; R8's WRITE_SIZE=115MB on a
// 67MB output + ~8MB out-refetch is the partial-line-RMW smoking gun).
// Fix: stage the 16x128 f32 out-tile per chunk through padded LDS (obuf,
// stride 132, double-buffered so the existing per-chunk barrier orders
// writer(t+2) after reader(t)), then store one dwordx4/thread covering
// fully-dense 128B lines. Prefetch depth back to 1 (R8's depth-2 was
// neutral; frees regs for the epilogue under the 128-reg cap).

typedef __bf16 bf16;
typedef __attribute__((ext_vector_type(8))) __bf16 bf16x8;
typedef __attribute__((ext_vector_type(4))) __bf16 bf16x4;
typedef __attribute__((ext_vector_type(4))) float f32x4;

#define BATCH_ 65536
#define KDIM   512
#define NDIM   256
#define NHALF  128                 // N-cols per block
#define CHUNK_ROWS 16
#define CHUNKS 8                   // per block
#define ROWS_PER_BLOCK (CHUNK_ROWS * CHUNKS)   // 128
#define OPAD 132                   // obuf row stride in floats (bank stagger)

__global__ __launch_bounds__(256) void wcvt_kernel(const float* __restrict__ w,
                                                   bf16* __restrict__ wb) {
    int i = (blockIdx.x * 256 + threadIdx.x) * 4;
    f32x4 v = *(const f32x4*)(w + i);
    bf16x4 o;
    o[0] = (bf16)(v.x * 0.125f);
    o[1] = (bf16)(v.y * 0.125f);
    o[2] = (bf16)(v.z * 0.125f);
    o[3] = (bf16)(v.w * 0.125f);
    *(bf16x4*)(wb + i) = o;
}

// Issue 4 perfectly-linear global loads (64 B/thread, block covers 32 KB f32).
__device__ __forceinline__ void stage_issue(const float* xc, int tid, f32x4 (&r)[4]) {
#pragma unroll
    for (int i = 0; i < 4; ++i)
        r[i] = *(const f32x4*)((const char*)xc + i * 8192 + tid * 16);
}

// Convert to bf16, deposit into LDS with the bank swizzle.
// Thread t, pass i holds f32 elems [i*2048 + t*4 .. +4) -> logical bf16 byte
// L = i*4096 + t*8; row = i*4 + (t>>7); off = (t&127)*8;
// phys = row*1024 + (off ^ ((row&7)<<4)).
__device__ __forceinline__ void stage_write(bf16* buf, int tid, const f32x4 (&r)[4]) {
#pragma unroll
    for (int i = 0; i < 4; ++i) {
        const int row = i * 4 + (tid >> 7);
        const int off = (tid & 127) * 8;
        const int phys = row * 1024 + (off ^ ((row & 7) << 4));
        bf16x4 o;
        o[0] = (bf16)r[i].x;
        o[1] = (bf16)r[i].y;
        o[2] = (bf16)r[i].z;
        o[3] = (bf16)r[i].w;
        *(bf16x4*)((char*)buf + phys) = o;
    }
}

// Pure ds_read_b128 + MFMA, swizzled to spread l16 lanes across bank quads.
__device__ __forceinline__ void compute_chunk(const bf16* buf, const bf16x8 (&wf)[16],
                                              int l16, int q, f32x4& acc) {
    acc = (f32x4)0.0f;
    const char* base = (const char*)buf + l16 * 1024;
    const int xo = (l16 & 7) << 4;
#pragma unroll
    for (int kc = 0; kc < 16; ++kc) {
        bf16x8 a = *(const bf16x8*)(base + ((kc * 64 + q * 16) ^ xo));
        acc = __builtin_amdgcn_mfma_f32_16x16x32_bf16(a, wf[kc], acc, 0, 0, 0);
    }
}

// Deposit acc fragment into the padded out-staging tile.
// row = q*4+rr, col = w*16+l16. Stride 132: q-groups land 16 banks apart
// (2-way alias q vs q+2 -> free), l16 spans 16 distinct banks.
__device__ __forceinline__ void owrite(float* ob, int w, int l16, int q,
                                       const f32x4& acc) {
    float* p = ob + (q * 4) * OPAD + w * 16 + l16;
#pragma unroll
    for (int rr = 0; rr < 4; ++rr)
        p[rr * OPAD] = acc[rr];
}

// Coalesced store: thread t reads 16B contiguous from obuf and writes one
// dwordx4; a 32-thread row-group covers 512B dense (4 full 128B lines).
__device__ __forceinline__ void ostore(const float* ob, float* __restrict__ out,
                                       long row0, int half, int tid,
                                       const f32x4& bvv) {
    const int r2 = tid >> 5;
    const int c4 = (tid & 31) * 4;
    f32x4 v = *(const f32x4*)(ob + r2 * OPAD + c4);
    v.x += bvv.x; v.y += bvv.y; v.z += bvv.z; v.w += bvv.w;
    *(f32x4*)(out + (row0 + r2) * NDIM + half * NHALF + c4) = v;
}

// LDS-visibility barrier WITHOUT the vmcnt(0) drain __syncthreads would emit.
__device__ __forceinline__ void lds_barrier() {
    asm volatile("s_waitcnt lgkmcnt(0)" ::: "memory");
    __builtin_amdgcn_s_barrier();
    __builtin_amdgcn_sched_barrier(0);
}

__global__ __launch_bounds__(512, 4) void gemm_kernel(const float* __restrict__ x,
                                                      const bf16* __restrict__ wb,
                                                      const float* __restrict__ bias,
                                                      float* __restrict__ out) {
    __shared__ __align__(16) bf16 bufA[CHUNK_ROWS * KDIM];   // 16 KB
    __shared__ __align__(16) bf16 bufB[CHUNK_ROWS * KDIM];   // 16 KB
    __shared__ __align__(16) float obuf0[CHUNK_ROWS * OPAD]; // 8.25 KB
    __shared__ __align__(16) float obuf1[CHUNK_ROWS * OPAD]; // 8.25 KB

    const int tid  = threadIdx.x;
    const int lane = tid & 63;
    const int w    = tid >> 6;     // wave 0..7 -> 16 N-columns each
    const int q    = lane >> 4;
    const int l16  = lane & 15;

    // Pair N-halves on the SAME XCD: g and g+8 share rb, differ in half.
    const int g    = blockIdx.x;
    const int half = (g >> 3) & 1;
    const long rb  = (long)((g & 7) | ((g >> 4) << 3));
    const int n0   = half * NHALF + w * 16;
    const long row_base = rb * ROWS_PER_BLOCK;

    // Stationary W: wf[kc] = W[n0+l16][kc*32+q*8 .. +7]  (64 regs/wave)
    bf16x8 wf[16];
#pragma unroll
    for (int kc = 0; kc < 16; ++kc)
        wf[kc] = *(const bf16x8*)(wb + (long)(n0 + l16) * KDIM + kc * 32 + q * 8);

    // Per-thread bias fragment for the coalesced epilogue.
    f32x4 bvv;
    {
        f32x4 b = *(const f32x4*)(bias + half * NHALF + (tid & 31) * 4);
        bvv.x = 0.1f * b.x; bvv.y = 0.1f * b.y;
        bvv.z = 0.1f * b.z; bvv.w = 0.1f * b.w;
    }

    const float* xblk = x + row_base * KDIM;

    // Prologue: chunk 0 -> bufA.
    f32x4 r[4];
    stage_issue(xblk, tid, r);
    stage_write(bufA, tid, r);
    lds_barrier();

    f32x4 acc;
#pragma unroll 1
    for (int t = 0; t < CHUNKS; t += 2) {
        // ---- even chunk t: compute bufA -> obuf0; prefetch t+1 -> bufB ----
        if (t + 1 < CHUNKS)
            stage_issue(xblk + (long)(t + 1) * CHUNK_ROWS * KDIM, tid, r);
        compute_chunk(bufA, wf, l16, q, acc);
        owrite(obuf0, w, l16, q, acc);
        if (t + 1 < CHUNKS)
            stage_write(bufB, tid, r);
        lds_barrier();
        ostore(obuf0, out, row_base + (long)t * CHUNK_ROWS, half, tid, bvv);

        // ---- odd chunk t+1: compute bufB -> obuf1; prefetch t+2 -> bufA ----
        if (t + 2 < CHUNKS)
            stage_issue(xblk + (long)(t + 2) * CHUNK_ROWS * KDIM, tid, r);
        compute_chunk(bufB, wf, l16, q, acc);
        owrite(obuf1, w, l16, q, acc);
        if (t + 2 < CHUNKS)
            stage_write(bufA, tid, r);
        lds_barrier();
        ostore(obuf1, out, row_base + (long)(t + 1) * CHUNK_ROWS, half, tid, bvv);
    }
}

extern "C" void kernel_launch(void* const* d_in, const int* in_sizes, int n_in,
                              void* d_out, int out_size, void* d_ws, size_t ws_size,
                              hipStream_t stream) {
    const float* x    = (const float*)d_in[0];
    const float* w    = (const float*)d_in[1];
    const float* bias = (const float*)d_in[2];
    float* out = (float*)d_out;
    bf16* wb   = (bf16*)d_ws;   // 256*512*2 = 256 KB scratch

    wcvt_kernel<<<(NDIM * KDIM) / (256 * 4), 256, 0, stream>>>(w, wb);
    gemm_kernel<<<(BATCH_ / ROWS_PER_BLOCK) * 2, 512, 0, stream>>>(x, wb, bias, out);
}